// Round 12
// baseline (157.110 us; speedup 1.0000x reference)
//
#include <hip/hip_runtime.h>
#include <hip/hip_fp16.h>

#define NNODES 50000
#define NEDGES 800000
#define DIM    128
#define NGRAPH 512
#define NSLAB  3125   // 50000/16
#define EPB    2048   // edges per block (build passes), 8/thread
#define NBLK_E 391    // ceil(800000/2048)
#define NBUCK  196    // node buckets of 256
#define HSTRIDE NBLK_E

typedef _Float16 f16x8 __attribute__((ext_vector_type(8)));
typedef float    f32x4 __attribute__((ext_vector_type(4)));
union U4H8 { uint4 u; f16x8 h; };

// ---------- pass A: per-(bucket,block) histogram via LDS; tail blocks do W->fp16 transpose ----------
__global__ void __launch_bounds__(256) bucket_hist(const int* __restrict__ dst,
                                                   int* __restrict__ hist,
                                                   const float* __restrict__ W1,
                                                   const float* __restrict__ W2,
                                                   __half* __restrict__ Wt1,
                                                   __half* __restrict__ Wt2) {
    int t = threadIdx.x;
    if (blockIdx.x >= NBLK_E) {   // W transpose: 16 blocks x 256 threads = 4096 items
        int i = (blockIdx.x - NBLK_E) * 256 + t;
        const float* W = (i < 2048) ? W1 : W2;
        __half* Wt = (i < 2048) ? Wt1 : Wt2;
        int j = i & 2047;
        int c  = j >> 4;
        int k0 = (j & 15) * 8;
        __half tmp[8];
        #pragma unroll
        for (int u = 0; u < 8; ++u) tmp[u] = (__half)W[(size_t)(k0 + u) * DIM + c];
        *(uint4*)(Wt + (size_t)c * DIM + k0) = *(uint4*)tmp;
        return;
    }
    __shared__ int cnt[NBUCK];
    if (t < NBUCK) cnt[t] = 0;
    __syncthreads();
    int e0 = blockIdx.x * EPB + t * 8;
    if (e0 + 7 < NEDGES) {
        int4 d0 = *(const int4*)(dst + e0);
        int4 d1 = *(const int4*)(dst + e0 + 4);
        atomicAdd(&cnt[d0.x >> 8], 1);
        atomicAdd(&cnt[d0.y >> 8], 1);
        atomicAdd(&cnt[d0.z >> 8], 1);
        atomicAdd(&cnt[d0.w >> 8], 1);
        atomicAdd(&cnt[d1.x >> 8], 1);
        atomicAdd(&cnt[d1.y >> 8], 1);
        atomicAdd(&cnt[d1.z >> 8], 1);
        atomicAdd(&cnt[d1.w >> 8], 1);
    }
    __syncthreads();
    if (t < NBUCK) hist[t * HSTRIDE + blockIdx.x] = cnt[t];
}

// ---------- S1: per-bucket exclusive scan of its 391 per-block counts (in place) + total ----------
__global__ void __launch_bounds__(512) scan1(int* __restrict__ hist, int* __restrict__ btot) {
    __shared__ int s[512];
    int b = blockIdx.x;
    int t = threadIdx.x;
    int v = (t < HSTRIDE) ? hist[b * HSTRIDE + t] : 0;
    s[t] = v;
    __syncthreads();
    #pragma unroll
    for (int o = 1; o < 512; o <<= 1) {
        int u = (t >= o) ? s[t - o] : 0;
        __syncthreads();
        s[t] += u;
        __syncthreads();
    }
    if (t < HSTRIDE) hist[b * HSTRIDE + t] = s[t] - v;   // within-bucket exclusive
    if (t == 511) btot[b] = s[511];
}

// ---------- S2: exclusive scan of 196 bucket totals -> base[197] ----------
__global__ void __launch_bounds__(256) scan2(const int* __restrict__ btot, int* __restrict__ base) {
    __shared__ int s[256];
    int t = threadIdx.x;
    int v = (t < NBUCK) ? btot[t] : 0;
    s[t] = v;
    __syncthreads();
    #pragma unroll
    for (int o = 1; o < 256; o <<= 1) {
        int u = (t >= o) ? s[t - o] : 0;
        __syncthreads();
        s[t] += u;
        __syncthreads();
    }
    if (t < NBUCK) base[t] = s[t] - v;
    if (t == 255) base[NBUCK] = s[255];   // = NEDGES
}

// ---------- pass C: scatter packed (src | (dst&255)<<16) into bucket-partitioned ebuf ----------
__global__ void __launch_bounds__(256) bucket_scatter(const int* __restrict__ src,
                                                      const int* __restrict__ dst,
                                                      const int* __restrict__ hist,
                                                      const int* __restrict__ base,
                                                      unsigned* __restrict__ ebuf) {
    __shared__ int cnt[NBUCK];
    __shared__ int sbase[NBUCK];
    int t = threadIdx.x;
    if (t < NBUCK) { cnt[t] = 0; sbase[t] = base[t] + hist[t * HSTRIDE + blockIdx.x]; }
    __syncthreads();
    int e0 = blockIdx.x * EPB + t * 8;
    if (e0 + 7 < NEDGES) {
        int4 s0 = *(const int4*)(src + e0);
        int4 s1 = *(const int4*)(src + e0 + 4);
        int4 d0 = *(const int4*)(dst + e0);
        int4 d1 = *(const int4*)(dst + e0 + 4);
        int b, r;
        b = d0.x >> 8; r = atomicAdd(&cnt[b], 1); ebuf[sbase[b] + r] = (unsigned)s0.x | ((unsigned)(d0.x & 255) << 16);
        b = d0.y >> 8; r = atomicAdd(&cnt[b], 1); ebuf[sbase[b] + r] = (unsigned)s0.y | ((unsigned)(d0.y & 255) << 16);
        b = d0.z >> 8; r = atomicAdd(&cnt[b], 1); ebuf[sbase[b] + r] = (unsigned)s0.z | ((unsigned)(d0.z & 255) << 16);
        b = d0.w >> 8; r = atomicAdd(&cnt[b], 1); ebuf[sbase[b] + r] = (unsigned)s0.w | ((unsigned)(d0.w & 255) << 16);
        b = d1.x >> 8; r = atomicAdd(&cnt[b], 1); ebuf[sbase[b] + r] = (unsigned)s1.x | ((unsigned)(d1.x & 255) << 16);
        b = d1.y >> 8; r = atomicAdd(&cnt[b], 1); ebuf[sbase[b] + r] = (unsigned)s1.y | ((unsigned)(d1.y & 255) << 16);
        b = d1.z >> 8; r = atomicAdd(&cnt[b], 1); ebuf[sbase[b] + r] = (unsigned)s1.z | ((unsigned)(d1.z & 255) << 16);
        b = d1.w >> 8; r = atomicAdd(&cnt[b], 1); ebuf[sbase[b] + r] = (unsigned)s1.w | ((unsigned)(d1.w & 255) << 16);
    }
}

// ---------- pass D: per-bucket node sort -> deg/dis/rowstart + csr_src ----------
__global__ void __launch_bounds__(256) node_sort(const unsigned* __restrict__ ebuf,
                                                 const int* __restrict__ base,
                                                 int* __restrict__ rowstart,
                                                 float* __restrict__ dis,
                                                 int* __restrict__ csr_src) {
    __shared__ int cnt[256], cnt2[256], off[256], s[256];
    int b = blockIdx.x;
    int t = threadIdx.x;
    int start = base[b];
    int end   = base[b + 1];
    cnt[t] = 0; cnt2[t] = 0;
    __syncthreads();
    for (int i = start + t; i < end; i += 256)
        atomicAdd(&cnt[(ebuf[i] >> 16) & 255], 1);
    __syncthreads();
    s[t] = cnt[t];
    __syncthreads();
    #pragma unroll
    for (int o = 1; o < 256; o <<= 1) {
        int u = (t >= o) ? s[t - o] : 0;
        __syncthreads();
        s[t] += u;
        __syncthreads();
    }
    off[t] = s[t] - cnt[t];
    int node = b * 256 + t;
    if (node < NNODES) {
        rowstart[node] = start + off[t];
        dis[node] = rsqrtf((float)cnt[t] + 1.0f);
    }
    if (b == NBUCK - 1 && t == 0) rowstart[NNODES] = NEDGES;
    __syncthreads();
    for (int i = start + t; i < end; i += 256) {
        unsigned e = ebuf[i];
        int j = (e >> 16) & 255;
        int r = atomicAdd(&cnt2[j], 1);
        csr_src[start + off[j] + r] = (int)(e & 0xFFFFu);
    }
}

// ---------- MFMA fp16 GEMM: Yh[row] = fp16((X @ W)[row] * dis[row]) ----------
template<typename XT>
__global__ void __launch_bounds__(256) gemm_mfma(const XT* __restrict__ X,
                                                 const __half* __restrict__ Wt,
                                                 const float* __restrict__ dis,
                                                 __half* __restrict__ Y) {
    __shared__ __align__(16) unsigned char Wl[128 * 256];   // 32KB, XOR-swizzled rows

    const int t = threadIdx.x;
    {
        int col = t >> 1;
        int kb0 = (t & 1) * 128;
        const unsigned char* g = (const unsigned char*)Wt + col * 256 + kb0;
        #pragma unroll
        for (int i = 0; i < 8; ++i) {
            uint4 v = *(const uint4*)(g + i * 16);
            int kb = kb0 + i * 16;
            *(uint4*)(Wl + col * 256 + (kb ^ ((col & 7) << 4))) = v;
        }
    }
    __syncthreads();

    int wave = t >> 6;
    int slab = blockIdx.x * 4 + wave;
    if (slab >= NSLAB) return;
    int l  = t & 63;
    int lr = l & 15;
    int lg = l >> 4;

    int arow = slab * 16 + lr;

    f16x8 afr[4];
    if constexpr (sizeof(XT) == 4) {
        const float* xr = (const float*)X + (size_t)arow * DIM;
        #pragma unroll
        for (int c = 0; c < 4; ++c) {
            int k0 = c * 32 + lg * 8;
            float4 u0 = *(const float4*)(xr + k0);
            float4 u1 = *(const float4*)(xr + k0 + 4);
            f16x8 a;
            a[0] = (_Float16)u0.x; a[1] = (_Float16)u0.y;
            a[2] = (_Float16)u0.z; a[3] = (_Float16)u0.w;
            a[4] = (_Float16)u1.x; a[5] = (_Float16)u1.y;
            a[6] = (_Float16)u1.z; a[7] = (_Float16)u1.w;
            afr[c] = a;
        }
    } else {
        const __half* xr = (const __half*)X + (size_t)arow * DIM;
        #pragma unroll
        for (int c = 0; c < 4; ++c) {
            U4H8 u; u.u = *(const uint4*)(xr + c * 32 + lg * 8);
            afr[c] = u.h;
        }
    }

    f32x4 acc[8];
    #pragma unroll
    for (int jt = 0; jt < 8; ++jt) acc[jt] = (f32x4){0.f, 0.f, 0.f, 0.f};

    #pragma unroll
    for (int c = 0; c < 4; ++c) {
        #pragma unroll
        for (int jt = 0; jt < 8; ++jt) {
            int col = jt * 16 + lr;
            int kb  = c * 64 + lg * 16;
            U4H8 bb;
            bb.u = *(const uint4*)(Wl + col * 256 + (kb ^ ((col & 7) << 4)));
            acc[jt] = __builtin_amdgcn_mfma_f32_16x16x32_f16(afr[c], bb.h, acc[jt], 0, 0, 0);
        }
    }

    float4 dv = *(const float4*)(dis + slab * 16 + lg * 4);
    float dsc[4] = {dv.x, dv.y, dv.z, dv.w};
    #pragma unroll
    for (int j = 0; j < 4; ++j) {
        int row = slab * 16 + lg * 4 + j;
        __half* yr = Y + (size_t)row * DIM + lr;
        #pragma unroll
        for (int jt = 0; jt < 8; ++jt)
            yr[jt * 16] = (__half)(acc[jt][j] * dsc[j]);
    }
}

// ---------- GCN aggregate: fp16 gather-sum, fp32 accumulate, fp16 out ----------
__device__ __forceinline__ void acc_add(float4& a, uint2 u) {
    float2 f0 = __half22float2(*(__half2*)&u.x);
    float2 f1 = __half22float2(*(__half2*)&u.y);
    a.x += f0.x; a.y += f0.y; a.z += f1.x; a.w += f1.y;
}

__global__ void __launch_bounds__(256) gcn_gather(const __half* __restrict__ hwh,
                                                  const int* __restrict__ rowstart,
                                                  const int* __restrict__ csr_src,
                                                  const float* __restrict__ dis,
                                                  const float* __restrict__ b,
                                                  __half* __restrict__ outh) {
    int t = blockIdx.x * 256 + threadIdx.x;
    int d = t >> 5, q = t & 31;
    if (d >= NNODES) return;
    const uint2* hw8 = (const uint2*)hwh;

    float4 a0 = make_float4(0.f, 0.f, 0.f, 0.f);
    float4 a1 = a0, a2 = a0, a3 = a0, a4 = a0, a5 = a0, a6 = a0, a7 = a0;

    acc_add(a0, hw8[(size_t)d * 32 + q]);   // self-loop (pre-scaled)

    int beg = rowstart[d], end = rowstart[d + 1];
    int i = beg;
    for (; i + 8 <= end; i += 8) {
        int s0 = csr_src[i + 0], s1 = csr_src[i + 1];
        int s2 = csr_src[i + 2], s3 = csr_src[i + 3];
        int s4 = csr_src[i + 4], s5 = csr_src[i + 5];
        int s6 = csr_src[i + 6], s7 = csr_src[i + 7];
        uint2 v0 = hw8[(size_t)s0 * 32 + q];
        uint2 v1 = hw8[(size_t)s1 * 32 + q];
        uint2 v2 = hw8[(size_t)s2 * 32 + q];
        uint2 v3 = hw8[(size_t)s3 * 32 + q];
        uint2 v4 = hw8[(size_t)s4 * 32 + q];
        uint2 v5 = hw8[(size_t)s5 * 32 + q];
        uint2 v6 = hw8[(size_t)s6 * 32 + q];
        uint2 v7 = hw8[(size_t)s7 * 32 + q];
        acc_add(a0, v0); acc_add(a1, v1); acc_add(a2, v2); acc_add(a3, v3);
        acc_add(a4, v4); acc_add(a5, v5); acc_add(a6, v6); acc_add(a7, v7);
    }
    for (; i + 2 <= end; i += 2) {
        uint2 v0 = hw8[(size_t)csr_src[i + 0] * 32 + q];
        uint2 v1 = hw8[(size_t)csr_src[i + 1] * 32 + q];
        acc_add(a0, v0); acc_add(a1, v1);
    }
    if (i < end) acc_add(a0, hw8[(size_t)csr_src[i] * 32 + q]);

    a0.x += a1.x + a2.x + a3.x + a4.x + a5.x + a6.x + a7.x;
    a0.y += a1.y + a2.y + a3.y + a4.y + a5.y + a6.y + a7.y;
    a0.z += a1.z + a2.z + a3.z + a4.z + a5.z + a6.z + a7.z;
    a0.w += a1.w + a2.w + a3.w + a4.w + a5.w + a6.w + a7.w;

    float dd = dis[d];
    float4 bb = ((const float4*)b)[q];
    __half ot[4];
    ot[0] = (__half)fmaxf(fmaf(a0.x, dd, bb.x), 0.f);
    ot[1] = (__half)fmaxf(fmaf(a0.y, dd, bb.y), 0.f);
    ot[2] = (__half)fmaxf(fmaf(a0.z, dd, bb.z), 0.f);
    ot[3] = (__half)fmaxf(fmaf(a0.w, dd, bb.w), 0.f);
    ((uint2*)outh)[(size_t)d * 32 + q] = *(uint2*)ot;
}

// ---------- fused pooling + head: one 256-thread block per graph ----------
__device__ __forceinline__ int lower_bound_i(const int* __restrict__ a, int n, int v) {
    int lo = 0, hi = n;
    while (lo < hi) {
        int mid = (lo + hi) >> 1;
        if (a[mid] < v) lo = mid + 1; else hi = mid;
    }
    return lo;
}

__global__ void __launch_bounds__(256) pool_head(const __half* __restrict__ h,
                                                 const float* __restrict__ x,
                                                 const int* __restrict__ batch,
                                                 const int* __restrict__ xsrc,
                                                 const float* __restrict__ Wh,
                                                 const float* __restrict__ bh,
                                                 float* __restrict__ out) {
    __shared__ float sAG[DIM];
    __shared__ float sAC[DIM];
    __shared__ int   sSC;
    int g   = blockIdx.x;
    int t   = threadIdx.x;
    int sub = t >> 5;
    int q   = t & 31;

    if (t < DIM) { sAG[t] = 0.f; sAC[t] = 0.f; }
    if (t == 0) sSC = 0;
    __syncthreads();

    int lo = lower_bound_i(batch, NNODES, g);
    int hi = lower_bound_i(batch, NNODES, g + 1);

    float4 ag = make_float4(0.f, 0.f, 0.f, 0.f);
    float4 ac = make_float4(0.f, 0.f, 0.f, 0.f);
    int sc = 0;
    const uint2* h8 = (const uint2*)h;
    const float4* x4 = (const float4*)x;
    for (int r = lo + sub; r < hi; r += 8) {
        acc_add(ag, h8[(size_t)r * 32 + q]);
        if (xsrc[r] == 1) {
            float4 xv = x4[(size_t)r * 32 + q];
            ac.x += xv.x; ac.y += xv.y; ac.z += xv.z; ac.w += xv.w;
            sc++;
        }
    }
    float* agp = sAG + q * 4;
    atomicAdd(agp + 0, ag.x); atomicAdd(agp + 1, ag.y);
    atomicAdd(agp + 2, ag.z); atomicAdd(agp + 3, ag.w);
    float* acp = sAC + q * 4;
    atomicAdd(acp + 0, ac.x); atomicAdd(acp + 1, ac.y);
    atomicAdd(acp + 2, ac.z); atomicAdd(acp + 3, ac.w);
    if (q == 0 && sc) atomicAdd(&sSC, sc);
    __syncthreads();

    if (t < 32) {
        float invg = 1.0f / fmaxf((float)(hi - lo), 1.0f);
        float invc = 1.0f / fmaxf((float)sSC, 1.0f);
        const float2* Wh2 = (const float2*)Wh;
        float a0 = 0.f, a1 = 0.f;
        #pragma unroll
        for (int j = 0; j < 4; ++j) {
            float e1 = sAG[t * 4 + j] * invg;
            float2 w1 = Wh2[t * 4 + j];
            a0 = fmaf(e1, w1.x, a0);
            a1 = fmaf(e1, w1.y, a1);
            float e2 = sAC[t * 4 + j] * invc;
            float2 w2 = Wh2[DIM + t * 4 + j];
            a0 = fmaf(e2, w2.x, a0);
            a1 = fmaf(e2, w2.y, a1);
        }
        #pragma unroll
        for (int off = 16; off; off >>= 1) {
            a0 += __shfl_down(a0, off, 32);
            a1 += __shfl_down(a1, off, 32);
        }
        if (t == 0) {
            out[g * 2 + 0] = a0 + bh[0];
            out[g * 2 + 1] = a1 + bh[1];
        }
    }
}

extern "C" void kernel_launch(void* const* d_in, const int* in_sizes, int n_in,
                              void* d_out, int out_size, void* d_ws, size_t ws_size,
                              hipStream_t stream) {
    const float* x     = (const float*)d_in[0];
    const int*   ei    = (const int*)d_in[1];
    const int*   batch = (const int*)d_in[2];
    const int*   xsrc  = (const int*)d_in[3];
    const float* W1 = (const float*)d_in[4];
    const float* b1 = (const float*)d_in[5];
    const float* W2 = (const float*)d_in[6];
    const float* b2 = (const float*)d_in[7];
    const float* Wh = (const float*)d_in[8];
    const float* bh = (const float*)d_in[9];
    float* out = (float*)d_out;

    const int* src = ei;
    const int* dst = ei + NEDGES;

    // workspace layout (4-byte units)
    float* ws = (float*)d_ws;
    size_t off = 0;
    float*    dis      = ws + off;              off += 50048;
    int*      rowstart = (int*)(ws + off);      off += 50048;
    int*      hist     = (int*)(ws + off);      off += NBUCK * HSTRIDE + 64;  // 76,636
    int*      btot     = (int*)(ws + off);      off += 256;
    int*      base     = (int*)(ws + off);      off += 256;
    unsigned* ebuf     = (unsigned*)(ws + off); off += 800000;
    int*      csr_src  = (int*)(ws + off);      off += 800000;
    __half*   Wt1      = (__half*)(ws + off);   off += 8192;
    __half*   Wt2      = (__half*)(ws + off);   off += 8192;
    __half*   hwh      = (__half*)(ws + off);   off += (size_t)NNODES * DIM / 2;
    __half*   hbuf     = (__half*)(ws + off);   off += (size_t)NNODES * DIM / 2;

    // --- CSR build: LDS counting sort, 2-level scan, packed intermediate ---
    bucket_hist<<<NBLK_E + 16, 256, 0, stream>>>(dst, hist, W1, W2, Wt1, Wt2);
    scan1<<<NBUCK, 512, 0, stream>>>(hist, btot);
    scan2<<<1, 256, 0, stream>>>(btot, base);
    bucket_scatter<<<NBLK_E, 256, 0, stream>>>(src, dst, hist, base, ebuf);
    node_sort<<<NBUCK, 256, 0, stream>>>(ebuf, base, rowstart, dis, csr_src);

    const int ngemm = (NSLAB + 3) / 4;   // 782 blocks (4 waves/block)

    // --- layer 1: hwh = fp16((x@W1)*dis); h1 -> hbuf (fp16) ---
    gemm_mfma<float><<<ngemm, 256, 0, stream>>>(x, Wt1, dis, hwh);
    gcn_gather<<<(NNODES * 32) / 256, 256, 0, stream>>>(hwh, rowstart, csr_src, dis, b1, hbuf);

    // --- layer 2: hwh = fp16((h1@W2)*dis); h2 -> hbuf (fp16) ---
    gemm_mfma<__half><<<ngemm, 256, 0, stream>>>(hbuf, Wt2, dis, hwh);
    gcn_gather<<<(NNODES * 32) / 256, 256, 0, stream>>>(hwh, rowstart, csr_src, dis, b2, hbuf);

    // --- fused pooling + head ---
    pool_head<<<NGRAPH, 256, 0, stream>>>(hbuf, x, batch, xsrc, Wh, bh, out);
}

// Round 13
// 147.981 us; speedup vs baseline: 1.0617x; 1.0617x over previous
//
#include <hip/hip_runtime.h>
#include <hip/hip_fp16.h>

#define NNODES 50000
#define NEDGES 800000
#define DIM    128
#define NGRAPH 512
#define NSLAB  3125   // 50000/16
#define EPB    1024   // edges per block (build passes), 4/thread
#define NBLK_E 782    // ceil(800000/1024)
#define NBUCK  196    // node buckets of 256
#define HSTRIDE NBLK_E
#define NHIST  (NBUCK * HSTRIDE)      // 153,272
#define NSB1   ((NHIST + 255) / 256)  // 599

typedef _Float16 f16x8 __attribute__((ext_vector_type(8)));
typedef float    f32x4 __attribute__((ext_vector_type(4)));
union U4H8 { uint4 u; f16x8 h; };

// ---------- pass A: per-(bucket,block) LDS histogram; tail blocks do W->fp16 transpose ----------
__global__ void __launch_bounds__(256) bucket_hist(const int* __restrict__ dst,
                                                   int* __restrict__ hist,
                                                   const float* __restrict__ W1,
                                                   const float* __restrict__ W2,
                                                   __half* __restrict__ Wt1,
                                                   __half* __restrict__ Wt2) {
    int t = threadIdx.x;
    if (blockIdx.x >= NBLK_E) {   // W transpose: 16 blocks x 256 threads = 4096 items
        int i = (blockIdx.x - NBLK_E) * 256 + t;
        const float* W = (i < 2048) ? W1 : W2;
        __half* Wt = (i < 2048) ? Wt1 : Wt2;
        int j = i & 2047;
        int c  = j >> 4;
        int k0 = (j & 15) * 8;
        __half tmp[8];
        #pragma unroll
        for (int u = 0; u < 8; ++u) tmp[u] = (__half)W[(size_t)(k0 + u) * DIM + c];
        *(uint4*)(Wt + (size_t)c * DIM + k0) = *(uint4*)tmp;
        return;
    }
    __shared__ int cnt[NBUCK];
    if (t < NBUCK) cnt[t] = 0;
    __syncthreads();
    int e0 = blockIdx.x * EPB + t * 4;
    if (e0 + 3 < NEDGES) {
        int4 d = *(const int4*)(dst + e0);
        atomicAdd(&cnt[d.x >> 8], 1);
        atomicAdd(&cnt[d.y >> 8], 1);
        atomicAdd(&cnt[d.z >> 8], 1);
        atomicAdd(&cnt[d.w >> 8], 1);
    }
    __syncthreads();
    if (t < NBUCK) hist[t * HSTRIDE + blockIdx.x] = cnt[t];
}

// ---------- pass B: exclusive scan of hist[NHIST] (3 kernels, flat) ----------
__global__ void sb1(int* __restrict__ hist, int* __restrict__ partials) {
    __shared__ int s[256];
    int t = threadIdx.x;
    int gid = blockIdx.x * 256 + t;
    int v = (gid < NHIST) ? hist[gid] : 0;
    s[t] = v;
    __syncthreads();
    #pragma unroll
    for (int o = 1; o < 256; o <<= 1) {
        int u = (t >= o) ? s[t - o] : 0;
        __syncthreads();
        s[t] += u;
        __syncthreads();
    }
    if (gid < NHIST) hist[gid] = s[t] - v;
    if (t == 255) partials[blockIdx.x] = s[255];
}

__global__ void sb2(int* __restrict__ partials) {
    __shared__ int s[1024];
    int t = threadIdx.x;
    int v = (t < NSB1) ? partials[t] : 0;
    s[t] = v;
    __syncthreads();
    #pragma unroll
    for (int o = 1; o < 1024; o <<= 1) {
        int u = (t >= o) ? s[t - o] : 0;
        __syncthreads();
        s[t] += u;
        __syncthreads();
    }
    if (t < NSB1) partials[t] = s[t] - v;
}

__global__ void sb3(int* __restrict__ hist, const int* __restrict__ partials) {
    int gid = blockIdx.x * 256 + threadIdx.x;
    if (gid < NHIST) hist[gid] += partials[blockIdx.x];
}

// ---------- pass C: scatter packed (src | (dst&255)<<16) into bucket-partitioned ebuf ----------
__global__ void __launch_bounds__(256) bucket_scatter(const int* __restrict__ src,
                                                      const int* __restrict__ dst,
                                                      const int* __restrict__ hist,
                                                      unsigned* __restrict__ ebuf) {
    __shared__ int cnt[NBUCK];
    __shared__ int base[NBUCK];
    int t = threadIdx.x;
    if (t < NBUCK) { cnt[t] = 0; base[t] = hist[t * HSTRIDE + blockIdx.x]; }
    __syncthreads();
    int e0 = blockIdx.x * EPB + t * 4;
    if (e0 + 3 < NEDGES) {
        int4 s = *(const int4*)(src + e0);
        int4 d = *(const int4*)(dst + e0);
        int b, r;
        b = d.x >> 8; r = atomicAdd(&cnt[b], 1); ebuf[base[b] + r] = (unsigned)s.x | ((unsigned)(d.x & 255) << 16);
        b = d.y >> 8; r = atomicAdd(&cnt[b], 1); ebuf[base[b] + r] = (unsigned)s.y | ((unsigned)(d.y & 255) << 16);
        b = d.z >> 8; r = atomicAdd(&cnt[b], 1); ebuf[base[b] + r] = (unsigned)s.z | ((unsigned)(d.z & 255) << 16);
        b = d.w >> 8; r = atomicAdd(&cnt[b], 1); ebuf[base[b] + r] = (unsigned)s.w | ((unsigned)(d.w & 255) << 16);
    }
}

// ---------- pass D: per-bucket node sort -> deg/dis/rowstart + csr_src ----------
__global__ void __launch_bounds__(256) node_sort(const unsigned* __restrict__ ebuf,
                                                 const int* __restrict__ hist,
                                                 int* __restrict__ rowstart,
                                                 float* __restrict__ dis,
                                                 int* __restrict__ csr_src) {
    __shared__ int cnt[256], cnt2[256], off[256], s[256];
    int b = blockIdx.x;
    int t = threadIdx.x;
    int start = hist[b * HSTRIDE];
    int end = (b + 1 < NBUCK) ? hist[(b + 1) * HSTRIDE] : NEDGES;
    cnt[t] = 0; cnt2[t] = 0;
    __syncthreads();
    for (int i = start + t; i < end; i += 256)
        atomicAdd(&cnt[(ebuf[i] >> 16) & 255], 1);
    __syncthreads();
    s[t] = cnt[t];
    __syncthreads();
    #pragma unroll
    for (int o = 1; o < 256; o <<= 1) {
        int u = (t >= o) ? s[t - o] : 0;
        __syncthreads();
        s[t] += u;
        __syncthreads();
    }
    off[t] = s[t] - cnt[t];
    int node = b * 256 + t;
    if (node < NNODES) {
        rowstart[node] = start + off[t];
        dis[node] = rsqrtf((float)cnt[t] + 1.0f);
    }
    if (b == NBUCK - 1 && t == 0) rowstart[NNODES] = NEDGES;
    __syncthreads();
    for (int i = start + t; i < end; i += 256) {
        unsigned e = ebuf[i];
        int j = (e >> 16) & 255;
        int r = atomicAdd(&cnt2[j], 1);
        csr_src[start + off[j] + r] = (int)(e & 0xFFFFu);
    }
}

// ---------- MFMA fp16 GEMM: Yh[row] = fp16((X @ W)[row] * dis[row]) ----------
template<typename XT>
__global__ void __launch_bounds__(256) gemm_mfma(const XT* __restrict__ X,
                                                 const __half* __restrict__ Wt,
                                                 const float* __restrict__ dis,
                                                 __half* __restrict__ Y) {
    __shared__ __align__(16) unsigned char Wl[128 * 256];   // 32KB, XOR-swizzled rows

    const int t = threadIdx.x;
    {
        int col = t >> 1;
        int kb0 = (t & 1) * 128;
        const unsigned char* g = (const unsigned char*)Wt + col * 256 + kb0;
        #pragma unroll
        for (int i = 0; i < 8; ++i) {
            uint4 v = *(const uint4*)(g + i * 16);
            int kb = kb0 + i * 16;
            *(uint4*)(Wl + col * 256 + (kb ^ ((col & 7) << 4))) = v;
        }
    }
    __syncthreads();

    int wave = t >> 6;
    int slab = blockIdx.x * 4 + wave;
    if (slab >= NSLAB) return;
    int l  = t & 63;
    int lr = l & 15;
    int lg = l >> 4;

    int arow = slab * 16 + lr;

    f16x8 afr[4];
    if constexpr (sizeof(XT) == 4) {
        const float* xr = (const float*)X + (size_t)arow * DIM;
        #pragma unroll
        for (int c = 0; c < 4; ++c) {
            int k0 = c * 32 + lg * 8;
            float4 u0 = *(const float4*)(xr + k0);
            float4 u1 = *(const float4*)(xr + k0 + 4);
            f16x8 a;
            a[0] = (_Float16)u0.x; a[1] = (_Float16)u0.y;
            a[2] = (_Float16)u0.z; a[3] = (_Float16)u0.w;
            a[4] = (_Float16)u1.x; a[5] = (_Float16)u1.y;
            a[6] = (_Float16)u1.z; a[7] = (_Float16)u1.w;
            afr[c] = a;
        }
    } else {
        const __half* xr = (const __half*)X + (size_t)arow * DIM;
        #pragma unroll
        for (int c = 0; c < 4; ++c) {
            U4H8 u; u.u = *(const uint4*)(xr + c * 32 + lg * 8);
            afr[c] = u.h;
        }
    }

    f32x4 acc[8];
    #pragma unroll
    for (int jt = 0; jt < 8; ++jt) acc[jt] = (f32x4){0.f, 0.f, 0.f, 0.f};

    #pragma unroll
    for (int c = 0; c < 4; ++c) {
        #pragma unroll
        for (int jt = 0; jt < 8; ++jt) {
            int col = jt * 16 + lr;
            int kb  = c * 64 + lg * 16;
            U4H8 bb;
            bb.u = *(const uint4*)(Wl + col * 256 + (kb ^ ((col & 7) << 4)));
            acc[jt] = __builtin_amdgcn_mfma_f32_16x16x32_f16(afr[c], bb.h, acc[jt], 0, 0, 0);
        }
    }

    float4 dv = *(const float4*)(dis + slab * 16 + lg * 4);
    float dsc[4] = {dv.x, dv.y, dv.z, dv.w};
    #pragma unroll
    for (int j = 0; j < 4; ++j) {
        int row = slab * 16 + lg * 4 + j;
        __half* yr = Y + (size_t)row * DIM + lr;
        #pragma unroll
        for (int jt = 0; jt < 8; ++jt)
            yr[jt * 16] = (__half)(acc[jt][j] * dsc[j]);
    }
}

// ---------- GCN aggregate: fp16 gather-sum, fp32 accumulate, fp16 out ----------
__device__ __forceinline__ void acc_add(float4& a, uint2 u) {
    float2 f0 = __half22float2(*(__half2*)&u.x);
    float2 f1 = __half22float2(*(__half2*)&u.y);
    a.x += f0.x; a.y += f0.y; a.z += f1.x; a.w += f1.y;
}

__global__ void __launch_bounds__(256) gcn_gather(const __half* __restrict__ hwh,
                                                  const int* __restrict__ rowstart,
                                                  const int* __restrict__ csr_src,
                                                  const float* __restrict__ dis,
                                                  const float* __restrict__ b,
                                                  __half* __restrict__ outh) {
    int t = blockIdx.x * 256 + threadIdx.x;
    int d = t >> 5, q = t & 31;
    if (d >= NNODES) return;
    const uint2* hw8 = (const uint2*)hwh;

    float4 a0 = make_float4(0.f, 0.f, 0.f, 0.f);
    float4 a1 = a0, a2 = a0, a3 = a0, a4 = a0, a5 = a0, a6 = a0, a7 = a0;

    acc_add(a0, hw8[(size_t)d * 32 + q]);   // self-loop (pre-scaled)

    int beg = rowstart[d], end = rowstart[d + 1];
    int i = beg;
    for (; i + 8 <= end; i += 8) {
        int s0 = csr_src[i + 0], s1 = csr_src[i + 1];
        int s2 = csr_src[i + 2], s3 = csr_src[i + 3];
        int s4 = csr_src[i + 4], s5 = csr_src[i + 5];
        int s6 = csr_src[i + 6], s7 = csr_src[i + 7];
        uint2 v0 = hw8[(size_t)s0 * 32 + q];
        uint2 v1 = hw8[(size_t)s1 * 32 + q];
        uint2 v2 = hw8[(size_t)s2 * 32 + q];
        uint2 v3 = hw8[(size_t)s3 * 32 + q];
        uint2 v4 = hw8[(size_t)s4 * 32 + q];
        uint2 v5 = hw8[(size_t)s5 * 32 + q];
        uint2 v6 = hw8[(size_t)s6 * 32 + q];
        uint2 v7 = hw8[(size_t)s7 * 32 + q];
        acc_add(a0, v0); acc_add(a1, v1); acc_add(a2, v2); acc_add(a3, v3);
        acc_add(a4, v4); acc_add(a5, v5); acc_add(a6, v6); acc_add(a7, v7);
    }
    for (; i + 2 <= end; i += 2) {
        uint2 v0 = hw8[(size_t)csr_src[i + 0] * 32 + q];
        uint2 v1 = hw8[(size_t)csr_src[i + 1] * 32 + q];
        acc_add(a0, v0); acc_add(a1, v1);
    }
    if (i < end) acc_add(a0, hw8[(size_t)csr_src[i] * 32 + q]);

    a0.x += a1.x + a2.x + a3.x + a4.x + a5.x + a6.x + a7.x;
    a0.y += a1.y + a2.y + a3.y + a4.y + a5.y + a6.y + a7.y;
    a0.z += a1.z + a2.z + a3.z + a4.z + a5.z + a6.z + a7.z;
    a0.w += a1.w + a2.w + a3.w + a4.w + a5.w + a6.w + a7.w;

    float dd = dis[d];
    float4 bb = ((const float4*)b)[q];
    __half ot[4];
    ot[0] = (__half)fmaxf(fmaf(a0.x, dd, bb.x), 0.f);
    ot[1] = (__half)fmaxf(fmaf(a0.y, dd, bb.y), 0.f);
    ot[2] = (__half)fmaxf(fmaf(a0.z, dd, bb.z), 0.f);
    ot[3] = (__half)fmaxf(fmaf(a0.w, dd, bb.w), 0.f);
    ((uint2*)outh)[(size_t)d * 32 + q] = *(uint2*)ot;
}

// ---------- fused pooling + head: one 256-thread block per graph ----------
__device__ __forceinline__ int lower_bound_i(const int* __restrict__ a, int n, int v) {
    int lo = 0, hi = n;
    while (lo < hi) {
        int mid = (lo + hi) >> 1;
        if (a[mid] < v) lo = mid + 1; else hi = mid;
    }
    return lo;
}

__global__ void __launch_bounds__(256) pool_head(const __half* __restrict__ h,
                                                 const float* __restrict__ x,
                                                 const int* __restrict__ batch,
                                                 const int* __restrict__ xsrc,
                                                 const float* __restrict__ Wh,
                                                 const float* __restrict__ bh,
                                                 float* __restrict__ out) {
    __shared__ float sAG[DIM];
    __shared__ float sAC[DIM];
    __shared__ int   sSC;
    int g   = blockIdx.x;
    int t   = threadIdx.x;
    int sub = t >> 5;
    int q   = t & 31;

    if (t < DIM) { sAG[t] = 0.f; sAC[t] = 0.f; }
    if (t == 0) sSC = 0;
    __syncthreads();

    int lo = lower_bound_i(batch, NNODES, g);
    int hi = lower_bound_i(batch, NNODES, g + 1);

    float4 ag = make_float4(0.f, 0.f, 0.f, 0.f);
    float4 ac = make_float4(0.f, 0.f, 0.f, 0.f);
    int sc = 0;
    const uint2* h8 = (const uint2*)h;
    const float4* x4 = (const float4*)x;
    for (int r = lo + sub; r < hi; r += 8) {
        acc_add(ag, h8[(size_t)r * 32 + q]);
        if (xsrc[r] == 1) {
            float4 xv = x4[(size_t)r * 32 + q];
            ac.x += xv.x; ac.y += xv.y; ac.z += xv.z; ac.w += xv.w;
            sc++;
        }
    }
    float* agp = sAG + q * 4;
    atomicAdd(agp + 0, ag.x); atomicAdd(agp + 1, ag.y);
    atomicAdd(agp + 2, ag.z); atomicAdd(agp + 3, ag.w);
    float* acp = sAC + q * 4;
    atomicAdd(acp + 0, ac.x); atomicAdd(acp + 1, ac.y);
    atomicAdd(acp + 2, ac.z); atomicAdd(acp + 3, ac.w);
    if (q == 0 && sc) atomicAdd(&sSC, sc);
    __syncthreads();

    if (t < 32) {
        float invg = 1.0f / fmaxf((float)(hi - lo), 1.0f);
        float invc = 1.0f / fmaxf((float)sSC, 1.0f);
        const float2* Wh2 = (const float2*)Wh;
        float a0 = 0.f, a1 = 0.f;
        #pragma unroll
        for (int j = 0; j < 4; ++j) {
            float e1 = sAG[t * 4 + j] * invg;
            float2 w1 = Wh2[t * 4 + j];
            a0 = fmaf(e1, w1.x, a0);
            a1 = fmaf(e1, w1.y, a1);
            float e2 = sAC[t * 4 + j] * invc;
            float2 w2 = Wh2[DIM + t * 4 + j];
            a0 = fmaf(e2, w2.x, a0);
            a1 = fmaf(e2, w2.y, a1);
        }
        #pragma unroll
        for (int off = 16; off; off >>= 1) {
            a0 += __shfl_down(a0, off, 32);
            a1 += __shfl_down(a1, off, 32);
        }
        if (t == 0) {
            out[g * 2 + 0] = a0 + bh[0];
            out[g * 2 + 1] = a1 + bh[1];
        }
    }
}

extern "C" void kernel_launch(void* const* d_in, const int* in_sizes, int n_in,
                              void* d_out, int out_size, void* d_ws, size_t ws_size,
                              hipStream_t stream) {
    const float* x     = (const float*)d_in[0];
    const int*   ei    = (const int*)d_in[1];
    const int*   batch = (const int*)d_in[2];
    const int*   xsrc  = (const int*)d_in[3];
    const float* W1 = (const float*)d_in[4];
    const float* b1 = (const float*)d_in[5];
    const float* W2 = (const float*)d_in[6];
    const float* b2 = (const float*)d_in[7];
    const float* Wh = (const float*)d_in[8];
    const float* bh = (const float*)d_in[9];
    float* out = (float*)d_out;

    const int* src = ei;
    const int* dst = ei + NEDGES;

    // workspace layout (4-byte units)
    float* ws = (float*)d_ws;
    size_t off = 0;
    float*    dis      = ws + off;              off += 50048;
    int*      rowstart = (int*)(ws + off);      off += 50048;
    int*      hist     = (int*)(ws + off);      off += ((NHIST + 255) & ~255);
    int*      partials = (int*)(ws + off);      off += 1024;
    unsigned* ebuf     = (unsigned*)(ws + off); off += 800000;
    int*      csr_src  = (int*)(ws + off);      off += 800000;
    __half*   Wt1      = (__half*)(ws + off);   off += 8192;
    __half*   Wt2      = (__half*)(ws + off);   off += 8192;
    __half*   hwh      = (__half*)(ws + off);   off += (size_t)NNODES * DIM / 2;
    __half*   hbuf     = (__half*)(ws + off);   off += (size_t)NNODES * DIM / 2;

    // --- CSR build: LDS counting sort (round-11 shape, packed ebuf, fused prep_w) ---
    bucket_hist<<<NBLK_E + 16, 256, 0, stream>>>(dst, hist, W1, W2, Wt1, Wt2);
    sb1<<<NSB1, 256, 0, stream>>>(hist, partials);
    sb2<<<1, 1024, 0, stream>>>(partials);
    sb3<<<NSB1, 256, 0, stream>>>(hist, partials);
    bucket_scatter<<<NBLK_E, 256, 0, stream>>>(src, dst, hist, ebuf);
    node_sort<<<NBUCK, 256, 0, stream>>>(ebuf, hist, rowstart, dis, csr_src);

    const int ngemm = (NSLAB + 3) / 4;   // 782 blocks (4 waves/block)

    // --- layer 1: hwh = fp16((x@W1)*dis); h1 -> hbuf (fp16) ---
    gemm_mfma<float><<<ngemm, 256, 0, stream>>>(x, Wt1, dis, hwh);
    gcn_gather<<<(NNODES * 32) / 256, 256, 0, stream>>>(hwh, rowstart, csr_src, dis, b1, hbuf);

    // --- layer 2: hwh = fp16((h1@W2)*dis); h2 -> hbuf (fp16) ---
    gemm_mfma<__half><<<ngemm, 256, 0, stream>>>(hbuf, Wt2, dis, hwh);
    gcn_gather<<<(NNODES * 32) / 256, 256, 0, stream>>>(hwh, rowstart, csr_src, dis, b2, hbuf);

    // --- fused pooling + head ---
    pool_head<<<NGRAPH, 256, 0, stream>>>(hbuf, x, batch, xsrc, Wh, bh, out);
}

// Round 14
// 145.655 us; speedup vs baseline: 1.0786x; 1.0160x over previous
//
#include <hip/hip_runtime.h>
#include <hip/hip_fp16.h>

#define NNODES 50000
#define NEDGES 800000
#define DIM    128
#define NGRAPH 512
#define NSLAB  3125   // 50000/16
#define EPB    1024   // edges per block (build passes), 4/thread
#define NBLK_E 782    // ceil(800000/1024)
#define NBUCK  196    // node buckets of 256
#define HSTRIDE NBLK_E
#define NHIST  (NBUCK * HSTRIDE)      // 153,272

typedef _Float16 f16x8 __attribute__((ext_vector_type(8)));
typedef float    f32x4 __attribute__((ext_vector_type(4)));
union U4H8 { uint4 u; f16x8 h; };

// ---------- pass A: per-(bucket,block) LDS histogram; tail blocks do W->fp16 transpose ----------
__global__ void __launch_bounds__(256) bucket_hist(const int* __restrict__ dst,
                                                   int* __restrict__ hist,
                                                   const float* __restrict__ W1,
                                                   const float* __restrict__ W2,
                                                   __half* __restrict__ Wt1,
                                                   __half* __restrict__ Wt2) {
    int t = threadIdx.x;
    if (blockIdx.x >= NBLK_E) {   // W transpose: 16 blocks x 256 threads = 4096 items
        int i = (blockIdx.x - NBLK_E) * 256 + t;
        const float* W = (i < 2048) ? W1 : W2;
        __half* Wt = (i < 2048) ? Wt1 : Wt2;
        int j = i & 2047;
        int c  = j >> 4;
        int k0 = (j & 15) * 8;
        __half tmp[8];
        #pragma unroll
        for (int u = 0; u < 8; ++u) tmp[u] = (__half)W[(size_t)(k0 + u) * DIM + c];
        *(uint4*)(Wt + (size_t)c * DIM + k0) = *(uint4*)tmp;
        return;
    }
    __shared__ int cnt[NBUCK];
    if (t < NBUCK) cnt[t] = 0;
    __syncthreads();
    int e0 = blockIdx.x * EPB + t * 4;
    if (e0 + 3 < NEDGES) {
        int4 d = *(const int4*)(dst + e0);
        atomicAdd(&cnt[d.x >> 8], 1);
        atomicAdd(&cnt[d.y >> 8], 1);
        atomicAdd(&cnt[d.z >> 8], 1);
        atomicAdd(&cnt[d.w >> 8], 1);
    }
    __syncthreads();
    if (t < NBUCK) hist[t * HSTRIDE + blockIdx.x] = cnt[t];
}

// ---------- pass B: per-bucket exclusive scan (in place) + bucket totals ----------
__global__ void __launch_bounds__(256) scan1(int* __restrict__ hist, int* __restrict__ btot) {
    __shared__ int s[256];
    int b = blockIdx.x;
    int t = threadIdx.x;
    int* hb = hist + b * HSTRIDE;
    int i0 = t * 4;
    int v[4];
    int loc = 0;
    #pragma unroll
    for (int u = 0; u < 4; ++u) {
        int idx = i0 + u;
        v[u] = (idx < HSTRIDE) ? hb[idx] : 0;
        loc += v[u];
    }
    s[t] = loc;
    __syncthreads();
    #pragma unroll
    for (int o = 1; o < 256; o <<= 1) {
        int u = (t >= o) ? s[t - o] : 0;
        __syncthreads();
        s[t] += u;
        __syncthreads();
    }
    int run = s[t] - loc;   // exclusive base for this thread's 4 entries
    #pragma unroll
    for (int u = 0; u < 4; ++u) {
        int idx = i0 + u;
        if (idx < HSTRIDE) hb[idx] = run;
        run += v[u];
    }
    if (t == 255) btot[b] = run;
}

// ---------- inline LDS exclusive scan of the 196 bucket totals ----------
__device__ __forceinline__ void base_scan(const int* __restrict__ btot, int* __restrict__ bex,
                                          int* __restrict__ s, int t) {
    int v = (t < NBUCK) ? btot[t] : 0;
    s[t] = v;
    __syncthreads();
    #pragma unroll
    for (int o = 1; o < 256; o <<= 1) {
        int u = (t >= o) ? s[t - o] : 0;
        __syncthreads();
        s[t] += u;
        __syncthreads();
    }
    if (t < NBUCK) bex[t] = s[t] - v;
    if (t == 0) bex[NBUCK] = NEDGES;
    __syncthreads();
}

// ---------- pass C: scatter packed (src | (dst&255)<<16) into bucket-partitioned ebuf ----------
__global__ void __launch_bounds__(256) bucket_scatter(const int* __restrict__ src,
                                                      const int* __restrict__ dst,
                                                      const int* __restrict__ hist,
                                                      const int* __restrict__ btot,
                                                      unsigned* __restrict__ ebuf) {
    __shared__ int cnt[NBUCK];
    __shared__ int sbase[NBUCK];
    __shared__ int bex[NBUCK + 1];
    __shared__ int s[256];
    int t = threadIdx.x;
    base_scan(btot, bex, s, t);
    if (t < NBUCK) { cnt[t] = 0; sbase[t] = bex[t] + hist[t * HSTRIDE + blockIdx.x]; }
    __syncthreads();
    int e0 = blockIdx.x * EPB + t * 4;
    if (e0 + 3 < NEDGES) {
        int4 sv = *(const int4*)(src + e0);
        int4 d = *(const int4*)(dst + e0);
        int b, r;
        b = d.x >> 8; r = atomicAdd(&cnt[b], 1); ebuf[sbase[b] + r] = (unsigned)sv.x | ((unsigned)(d.x & 255) << 16);
        b = d.y >> 8; r = atomicAdd(&cnt[b], 1); ebuf[sbase[b] + r] = (unsigned)sv.y | ((unsigned)(d.y & 255) << 16);
        b = d.z >> 8; r = atomicAdd(&cnt[b], 1); ebuf[sbase[b] + r] = (unsigned)sv.z | ((unsigned)(d.z & 255) << 16);
        b = d.w >> 8; r = atomicAdd(&cnt[b], 1); ebuf[sbase[b] + r] = (unsigned)sv.w | ((unsigned)(d.w & 255) << 16);
    }
}

// ---------- pass D: per-bucket node sort -> deg/dis/rowstart + csr_src ----------
__global__ void __launch_bounds__(256) node_sort(const unsigned* __restrict__ ebuf,
                                                 const int* __restrict__ btot,
                                                 int* __restrict__ rowstart,
                                                 float* __restrict__ dis,
                                                 int* __restrict__ csr_src) {
    __shared__ int cnt[256], cnt2[256], off[256], s[256];
    __shared__ int bex[NBUCK + 1];
    int b = blockIdx.x;
    int t = threadIdx.x;
    base_scan(btot, bex, s, t);
    int start = bex[b];
    int end   = bex[b + 1];
    cnt[t] = 0; cnt2[t] = 0;
    __syncthreads();
    for (int i = start + t; i < end; i += 256)
        atomicAdd(&cnt[(ebuf[i] >> 16) & 255], 1);
    __syncthreads();
    s[t] = cnt[t];
    __syncthreads();
    #pragma unroll
    for (int o = 1; o < 256; o <<= 1) {
        int u = (t >= o) ? s[t - o] : 0;
        __syncthreads();
        s[t] += u;
        __syncthreads();
    }
    off[t] = s[t] - cnt[t];
    int node = b * 256 + t;
    if (node < NNODES) {
        rowstart[node] = start + off[t];
        dis[node] = rsqrtf((float)cnt[t] + 1.0f);
    }
    if (b == NBUCK - 1 && t == 0) rowstart[NNODES] = NEDGES;
    __syncthreads();
    for (int i = start + t; i < end; i += 256) {
        unsigned e = ebuf[i];
        int j = (e >> 16) & 255;
        int r = atomicAdd(&cnt2[j], 1);
        csr_src[start + off[j] + r] = (int)(e & 0xFFFFu);
    }
}

// ---------- MFMA fp16 GEMM: Yh[row] = fp16((X @ W)[row] * dis[row]) ----------
template<typename XT>
__global__ void __launch_bounds__(256) gemm_mfma(const XT* __restrict__ X,
                                                 const __half* __restrict__ Wt,
                                                 const float* __restrict__ dis,
                                                 __half* __restrict__ Y) {
    __shared__ __align__(16) unsigned char Wl[128 * 256];   // 32KB, XOR-swizzled rows

    const int t = threadIdx.x;
    {
        int col = t >> 1;
        int kb0 = (t & 1) * 128;
        const unsigned char* g = (const unsigned char*)Wt + col * 256 + kb0;
        #pragma unroll
        for (int i = 0; i < 8; ++i) {
            uint4 v = *(const uint4*)(g + i * 16);
            int kb = kb0 + i * 16;
            *(uint4*)(Wl + col * 256 + (kb ^ ((col & 7) << 4))) = v;
        }
    }
    __syncthreads();

    int wave = t >> 6;
    int slab = blockIdx.x * 4 + wave;
    if (slab >= NSLAB) return;
    int l  = t & 63;
    int lr = l & 15;
    int lg = l >> 4;

    int arow = slab * 16 + lr;

    f16x8 afr[4];
    if constexpr (sizeof(XT) == 4) {
        const float* xr = (const float*)X + (size_t)arow * DIM;
        #pragma unroll
        for (int c = 0; c < 4; ++c) {
            int k0 = c * 32 + lg * 8;
            float4 u0 = *(const float4*)(xr + k0);
            float4 u1 = *(const float4*)(xr + k0 + 4);
            f16x8 a;
            a[0] = (_Float16)u0.x; a[1] = (_Float16)u0.y;
            a[2] = (_Float16)u0.z; a[3] = (_Float16)u0.w;
            a[4] = (_Float16)u1.x; a[5] = (_Float16)u1.y;
            a[6] = (_Float16)u1.z; a[7] = (_Float16)u1.w;
            afr[c] = a;
        }
    } else {
        const __half* xr = (const __half*)X + (size_t)arow * DIM;
        #pragma unroll
        for (int c = 0; c < 4; ++c) {
            U4H8 u; u.u = *(const uint4*)(xr + c * 32 + lg * 8);
            afr[c] = u.h;
        }
    }

    f32x4 acc[8];
    #pragma unroll
    for (int jt = 0; jt < 8; ++jt) acc[jt] = (f32x4){0.f, 0.f, 0.f, 0.f};

    #pragma unroll
    for (int c = 0; c < 4; ++c) {
        #pragma unroll
        for (int jt = 0; jt < 8; ++jt) {
            int col = jt * 16 + lr;
            int kb  = c * 64 + lg * 16;
            U4H8 bb;
            bb.u = *(const uint4*)(Wl + col * 256 + (kb ^ ((col & 7) << 4)));
            acc[jt] = __builtin_amdgcn_mfma_f32_16x16x32_f16(afr[c], bb.h, acc[jt], 0, 0, 0);
        }
    }

    float4 dv = *(const float4*)(dis + slab * 16 + lg * 4);
    float dsc[4] = {dv.x, dv.y, dv.z, dv.w};
    #pragma unroll
    for (int j = 0; j < 4; ++j) {
        int row = slab * 16 + lg * 4 + j;
        __half* yr = Y + (size_t)row * DIM + lr;
        #pragma unroll
        for (int jt = 0; jt < 8; ++jt)
            yr[jt * 16] = (__half)(acc[jt][j] * dsc[j]);
    }
}

// ---------- GCN aggregate: fp16 gather-sum, fp32 accumulate, fp16 out ----------
__device__ __forceinline__ void acc_add(float4& a, uint2 u) {
    float2 f0 = __half22float2(*(__half2*)&u.x);
    float2 f1 = __half22float2(*(__half2*)&u.y);
    a.x += f0.x; a.y += f0.y; a.z += f1.x; a.w += f1.y;
}

__global__ void __launch_bounds__(256) gcn_gather(const __half* __restrict__ hwh,
                                                  const int* __restrict__ rowstart,
                                                  const int* __restrict__ csr_src,
                                                  const float* __restrict__ dis,
                                                  const float* __restrict__ b,
                                                  __half* __restrict__ outh) {
    int t = blockIdx.x * 256 + threadIdx.x;
    int d = t >> 5, q = t & 31;
    if (d >= NNODES) return;
    const uint2* hw8 = (const uint2*)hwh;

    float4 a0 = make_float4(0.f, 0.f, 0.f, 0.f);
    float4 a1 = a0, a2 = a0, a3 = a0, a4 = a0, a5 = a0, a6 = a0, a7 = a0;

    acc_add(a0, hw8[(size_t)d * 32 + q]);   // self-loop (pre-scaled)

    int beg = rowstart[d], end = rowstart[d + 1];
    int i = beg;
    for (; i + 8 <= end; i += 8) {
        int s0 = csr_src[i + 0], s1 = csr_src[i + 1];
        int s2 = csr_src[i + 2], s3 = csr_src[i + 3];
        int s4 = csr_src[i + 4], s5 = csr_src[i + 5];
        int s6 = csr_src[i + 6], s7 = csr_src[i + 7];
        uint2 v0 = hw8[(size_t)s0 * 32 + q];
        uint2 v1 = hw8[(size_t)s1 * 32 + q];
        uint2 v2 = hw8[(size_t)s2 * 32 + q];
        uint2 v3 = hw8[(size_t)s3 * 32 + q];
        uint2 v4 = hw8[(size_t)s4 * 32 + q];
        uint2 v5 = hw8[(size_t)s5 * 32 + q];
        uint2 v6 = hw8[(size_t)s6 * 32 + q];
        uint2 v7 = hw8[(size_t)s7 * 32 + q];
        acc_add(a0, v0); acc_add(a1, v1); acc_add(a2, v2); acc_add(a3, v3);
        acc_add(a4, v4); acc_add(a5, v5); acc_add(a6, v6); acc_add(a7, v7);
    }
    for (; i + 2 <= end; i += 2) {
        uint2 v0 = hw8[(size_t)csr_src[i + 0] * 32 + q];
        uint2 v1 = hw8[(size_t)csr_src[i + 1] * 32 + q];
        acc_add(a0, v0); acc_add(a1, v1);
    }
    if (i < end) acc_add(a0, hw8[(size_t)csr_src[i] * 32 + q]);

    a0.x += a1.x + a2.x + a3.x + a4.x + a5.x + a6.x + a7.x;
    a0.y += a1.y + a2.y + a3.y + a4.y + a5.y + a6.y + a7.y;
    a0.z += a1.z + a2.z + a3.z + a4.z + a5.z + a6.z + a7.z;
    a0.w += a1.w + a2.w + a3.w + a4.w + a5.w + a6.w + a7.w;

    float dd = dis[d];
    float4 bb = ((const float4*)b)[q];
    __half ot[4];
    ot[0] = (__half)fmaxf(fmaf(a0.x, dd, bb.x), 0.f);
    ot[1] = (__half)fmaxf(fmaf(a0.y, dd, bb.y), 0.f);
    ot[2] = (__half)fmaxf(fmaf(a0.z, dd, bb.z), 0.f);
    ot[3] = (__half)fmaxf(fmaf(a0.w, dd, bb.w), 0.f);
    ((uint2*)outh)[(size_t)d * 32 + q] = *(uint2*)ot;
}

// ---------- fused pooling + head: one 256-thread block per graph ----------
__device__ __forceinline__ int lower_bound_i(const int* __restrict__ a, int n, int v) {
    int lo = 0, hi = n;
    while (lo < hi) {
        int mid = (lo + hi) >> 1;
        if (a[mid] < v) lo = mid + 1; else hi = mid;
    }
    return lo;
}

__global__ void __launch_bounds__(256) pool_head(const __half* __restrict__ h,
                                                 const float* __restrict__ x,
                                                 const int* __restrict__ batch,
                                                 const int* __restrict__ xsrc,
                                                 const float* __restrict__ Wh,
                                                 const float* __restrict__ bh,
                                                 float* __restrict__ out) {
    __shared__ float sAG[DIM];
    __shared__ float sAC[DIM];
    __shared__ int   sSC;
    int g   = blockIdx.x;
    int t   = threadIdx.x;
    int sub = t >> 5;
    int q   = t & 31;

    if (t < DIM) { sAG[t] = 0.f; sAC[t] = 0.f; }
    if (t == 0) sSC = 0;
    __syncthreads();

    int lo = lower_bound_i(batch, NNODES, g);
    int hi = lower_bound_i(batch, NNODES, g + 1);

    float4 ag = make_float4(0.f, 0.f, 0.f, 0.f);
    float4 ac = make_float4(0.f, 0.f, 0.f, 0.f);
    int sc = 0;
    const uint2* h8 = (const uint2*)h;
    const float4* x4 = (const float4*)x;
    for (int r = lo + sub; r < hi; r += 8) {
        acc_add(ag, h8[(size_t)r * 32 + q]);
        if (xsrc[r] == 1) {
            float4 xv = x4[(size_t)r * 32 + q];
            ac.x += xv.x; ac.y += xv.y; ac.z += xv.z; ac.w += xv.w;
            sc++;
        }
    }
    float* agp = sAG + q * 4;
    atomicAdd(agp + 0, ag.x); atomicAdd(agp + 1, ag.y);
    atomicAdd(agp + 2, ag.z); atomicAdd(agp + 3, ag.w);
    float* acp = sAC + q * 4;
    atomicAdd(acp + 0, ac.x); atomicAdd(acp + 1, ac.y);
    atomicAdd(acp + 2, ac.z); atomicAdd(acp + 3, ac.w);
    if (q == 0 && sc) atomicAdd(&sSC, sc);
    __syncthreads();

    if (t < 32) {
        float invg = 1.0f / fmaxf((float)(hi - lo), 1.0f);
        float invc = 1.0f / fmaxf((float)sSC, 1.0f);
        const float2* Wh2 = (const float2*)Wh;
        float a0 = 0.f, a1 = 0.f;
        #pragma unroll
        for (int j = 0; j < 4; ++j) {
            float e1 = sAG[t * 4 + j] * invg;
            float2 w1 = Wh2[t * 4 + j];
            a0 = fmaf(e1, w1.x, a0);
            a1 = fmaf(e1, w1.y, a1);
            float e2 = sAC[t * 4 + j] * invc;
            float2 w2 = Wh2[DIM + t * 4 + j];
            a0 = fmaf(e2, w2.x, a0);
            a1 = fmaf(e2, w2.y, a1);
        }
        #pragma unroll
        for (int off = 16; off; off >>= 1) {
            a0 += __shfl_down(a0, off, 32);
            a1 += __shfl_down(a1, off, 32);
        }
        if (t == 0) {
            out[g * 2 + 0] = a0 + bh[0];
            out[g * 2 + 1] = a1 + bh[1];
        }
    }
}

extern "C" void kernel_launch(void* const* d_in, const int* in_sizes, int n_in,
                              void* d_out, int out_size, void* d_ws, size_t ws_size,
                              hipStream_t stream) {
    const float* x     = (const float*)d_in[0];
    const int*   ei    = (const int*)d_in[1];
    const int*   batch = (const int*)d_in[2];
    const int*   xsrc  = (const int*)d_in[3];
    const float* W1 = (const float*)d_in[4];
    const float* b1 = (const float*)d_in[5];
    const float* W2 = (const float*)d_in[6];
    const float* b2 = (const float*)d_in[7];
    const float* Wh = (const float*)d_in[8];
    const float* bh = (const float*)d_in[9];
    float* out = (float*)d_out;

    const int* src = ei;
    const int* dst = ei + NEDGES;

    // workspace layout (4-byte units)
    float* ws = (float*)d_ws;
    size_t off = 0;
    float*    dis      = ws + off;              off += 50048;
    int*      rowstart = (int*)(ws + off);      off += 50048;
    int*      hist     = (int*)(ws + off);      off += ((NHIST + 255) & ~255);
    int*      btot     = (int*)(ws + off);      off += 256;
    unsigned* ebuf     = (unsigned*)(ws + off); off += 800000;
    int*      csr_src  = (int*)(ws + off);      off += 800000;
    __half*   Wt1      = (__half*)(ws + off);   off += 8192;
    __half*   Wt2      = (__half*)(ws + off);   off += 8192;
    __half*   hwh      = (__half*)(ws + off);   off += (size_t)NNODES * DIM / 2;
    __half*   hbuf     = (__half*)(ws + off);   off += (size_t)NNODES * DIM / 2;

    // --- CSR build: LDS counting sort, per-bucket scan + inline base reconstruction ---
    bucket_hist<<<NBLK_E + 16, 256, 0, stream>>>(dst, hist, W1, W2, Wt1, Wt2);
    scan1<<<NBUCK, 256, 0, stream>>>(hist, btot);
    bucket_scatter<<<NBLK_E, 256, 0, stream>>>(src, dst, hist, btot, ebuf);
    node_sort<<<NBUCK, 256, 0, stream>>>(ebuf, btot, rowstart, dis, csr_src);

    const int ngemm = (NSLAB + 3) / 4;   // 782 blocks (4 waves/block)

    // --- layer 1: hwh = fp16((x@W1)*dis); h1 -> hbuf (fp16) ---
    gemm_mfma<float><<<ngemm, 256, 0, stream>>>(x, Wt1, dis, hwh);
    gcn_gather<<<(NNODES * 32) / 256, 256, 0, stream>>>(hwh, rowstart, csr_src, dis, b1, hbuf);

    // --- layer 2: hwh = fp16((h1@W2)*dis); h2 -> hbuf (fp16) ---
    gemm_mfma<__half><<<ngemm, 256, 0, stream>>>(hbuf, Wt2, dis, hwh);
    gcn_gather<<<(NNODES * 32) / 256, 256, 0, stream>>>(hwh, rowstart, csr_src, dis, b2, hbuf);

    // --- fused pooling + head ---
    pool_head<<<NGRAPH, 256, 0, stream>>>(hbuf, x, batch, xsrc, Wh, bh, out);
}